// Round 8
// baseline (250.111 us; speedup 1.0000x reference)
//
#include <hip/hip_runtime.h>
#include <hip/hip_bf16.h>
#include <math.h>

#define NN 50000
#define EE 800000
#define FIN 256
#define HID 64
#define OUTD 64
#define H1 4
#define H2 1

typedef __attribute__((ext_vector_type(8))) short short8;
typedef __attribute__((ext_vector_type(4))) short short4v;
typedef __attribute__((ext_vector_type(4))) float f32x4;
typedef __attribute__((ext_vector_type(2))) float f32x2;

// ---------------- helpers ----------------

__device__ __forceinline__ unsigned short f2bf(float f) {   // round-to-nearest-even
    unsigned u = __float_as_uint(f);
    unsigned r = (u + 0x7FFFu + ((u >> 16) & 1u)) >> 16;
    return (unsigned short)r;
}
__device__ __forceinline__ float bf2f(unsigned short u) {
    return __uint_as_float(((unsigned)u) << 16);
}

// ---------------- CSR build ----------------

__global__ void hist_kernel(const int* __restrict__ dst, int* __restrict__ deg, int nE) {
    int e = blockIdx.x * 256 + threadIdx.x;
    if (e < nE) atomicAdd(&deg[dst[e]], 1);
}

__global__ void scan_block(const int* __restrict__ in, int* __restrict__ out,
                           int* __restrict__ bsums, int n) {
    __shared__ int sh[256];
    int i = blockIdx.x * 256 + threadIdx.x;
    int v = (i < n) ? in[i] : 0;
    sh[threadIdx.x] = v;
    __syncthreads();
    for (int off = 1; off < 256; off <<= 1) {
        int t = 0;
        if (threadIdx.x >= off) t = sh[threadIdx.x - off];
        __syncthreads();
        if (threadIdx.x >= off) sh[threadIdx.x] += t;
        __syncthreads();
    }
    if (i < n) out[i] = sh[threadIdx.x] - v;          // exclusive
    if (threadIdx.x == 255) bsums[blockIdx.x] = sh[255];
}

__global__ void scan_bsums(int* __restrict__ bsums, int nb) {
    __shared__ int sh[256];
    int v = (threadIdx.x < nb) ? bsums[threadIdx.x] : 0;
    sh[threadIdx.x] = v;
    __syncthreads();
    for (int off = 1; off < 256; off <<= 1) {
        int t = 0;
        if (threadIdx.x >= off) t = sh[threadIdx.x - off];
        __syncthreads();
        if (threadIdx.x >= off) sh[threadIdx.x] += t;
        __syncthreads();
    }
    if (threadIdx.x < nb) bsums[threadIdx.x] = sh[threadIdx.x] - v;  // exclusive
}

__global__ void add_offsets(int* __restrict__ out, const int* __restrict__ bsums,
                            int n, int Etot) {
    int i = blockIdx.x * 256 + threadIdx.x;
    if (i < n) out[i] += bsums[blockIdx.x];
    if (i == 0) out[n] = Etot;
}

__global__ void fill_csr(const int* __restrict__ src, const int* __restrict__ dst,
                         const int* __restrict__ rowptr, int* __restrict__ fillc,
                         int* __restrict__ csr_src, int nE) {
    int e = blockIdx.x * 256 + threadIdx.x;
    if (e < nE) {
        int d = dst[e];
        int pos = rowptr[d] + atomicAdd(&fillc[d], 1);
        csr_src[pos] = src[e];
    }
}

// ---------------- weight prep: transpose + split f32 -> bf16 hi/lo ----------------

__global__ void wsplit(const float* __restrict__ W1, const float* __restrict__ W2,
                       short* __restrict__ W1th, short* __restrict__ W1tl,
                       short* __restrict__ W2th, short* __restrict__ W2tl) {
    int n = blockIdx.x;
    int k = threadIdx.x;
    if (n < 256) {
        float v = W1[(size_t)k * 256 + n];
        unsigned short hi = f2bf(v);
        unsigned short lo = f2bf(v - bf2f(hi));
        W1th[n * 256 + k] = (short)hi;
        W1tl[n * 256 + k] = (short)lo;
    } else {
        int n2 = n - 256;
        float v = W2[(size_t)k * 64 + n2];
        unsigned short hi = f2bf(v);
        unsigned short lo = f2bf(v - bf2f(hi));
        W2th[n2 * 256 + k] = (short)hi;
        W2tl[n2 * 256 + k] = (short)lo;
    }
}

// ---------------- MFMA GEMM + fused scores epilogue ----------
// ASPLIT=true : A f32, split to hi/lo in staging, 3 MFMA passes.
// ASPLIT=false: A already bf16 (exact), 2 MFMA passes.

template<int MF, int WR, int WC, int NT, int H, bool ASPLIT>
__global__ __launch_bounds__(256) void gemm_bf16x2(
    const void* __restrict__ Av, const short* __restrict__ Bth, const short* __restrict__ Btl,
    const float* __restrict__ al, const float* __restrict__ ar,
    unsigned short* __restrict__ zb, float* __restrict__ el, float* __restrict__ er,
    int M, int K)
{
    constexpr int BM = WR * MF * 16;
    constexpr int BN = WC * 64;
    __shared__ short Ah[BM * 40];
    __shared__ short Al[ASPLIT ? BM * 40 : 8];
    __shared__ short Bh[BN * 40], Bl[BN * 40];

    const int bm = blockIdx.x * BM;
    const int bn = blockIdx.y * BN;
    const int t = threadIdx.x;
    const int wid = t >> 6;
    const int lane = t & 63;
    const int lr = lane & 15;
    const int lg = lane >> 4;
    const int wr = wid / WC;
    const int wc = wid % WC;

    f32x4 acc[MF][4];
#pragma unroll
    for (int mf = 0; mf < MF; ++mf)
#pragma unroll
        for (int nf = 0; nf < 4; ++nf) acc[mf][nf] = (f32x4)(0.f);

    for (int k0 = 0; k0 < K; k0 += 32) {
        if constexpr (ASPLIT) {
            const float* A = (const float*)Av;
#pragma unroll
            for (int q = 0; q < BM / 32; ++q) {
                int linear = q * 256 + t;
                int row = linear >> 3;
                int kq = (linear & 7) * 4;
                int grow = bm + row;
                float4 av = make_float4(0.f, 0.f, 0.f, 0.f);
                if (grow < M) av = *(const float4*)(A + (size_t)grow * K + k0 + kq);
                short4v hi, lo;
                unsigned short h0 = f2bf(av.x); hi.x = (short)h0; lo.x = (short)f2bf(av.x - bf2f(h0));
                unsigned short h1v = f2bf(av.y); hi.y = (short)h1v; lo.y = (short)f2bf(av.y - bf2f(h1v));
                unsigned short h2v = f2bf(av.z); hi.z = (short)h2v; lo.z = (short)f2bf(av.z - bf2f(h2v));
                unsigned short h3v = f2bf(av.w); hi.w = (short)h3v; lo.w = (short)f2bf(av.w - bf2f(h3v));
                *(short4v*)&Ah[row * 40 + kq] = hi;
                *(short4v*)&Al[row * 40 + kq] = lo;
            }
        } else {
            const unsigned short* A = (const unsigned short*)Av;
#pragma unroll
            for (int q = 0; q < BM / 64; ++q) {
                int linear = q * 256 + t;
                int row = linear >> 2;
                int k8 = (linear & 3) * 8;
                int grow = bm + row;
                short8 v = (short8)(0);
                if (grow < M) v = *(const short8*)(A + (size_t)grow * K + k0 + k8);
                *(short8*)&Ah[row * 40 + k8] = v;
            }
        }
#pragma unroll
        for (int q = 0; q < BN / 64; ++q) {
            int linear = q * 256 + t;
            int n = linear >> 2;
            int k8 = (linear & 3) * 8;
            short8 vh = *(const short8*)(Bth + (size_t)(bn + n) * K + k0 + k8);
            short8 vl = *(const short8*)(Btl + (size_t)(bn + n) * K + k0 + k8);
            *(short8*)&Bh[n * 40 + k8] = vh;
            *(short8*)&Bl[n * 40 + k8] = vl;
        }
        __syncthreads();

        short8 ah[MF], alo[MF], bh[4], blo[4];
#pragma unroll
        for (int mf = 0; mf < MF; ++mf) {
            int row = wr * MF * 16 + mf * 16 + lr;
            ah[mf] = *(const short8*)&Ah[row * 40 + lg * 8];
            if constexpr (ASPLIT) alo[mf] = *(const short8*)&Al[row * 40 + lg * 8];
        }
#pragma unroll
        for (int nf = 0; nf < 4; ++nf) {
            int col = wc * 64 + nf * 16 + lr;
            bh[nf]  = *(const short8*)&Bh[col * 40 + lg * 8];
            blo[nf] = *(const short8*)&Bl[col * 40 + lg * 8];
        }
#pragma unroll
        for (int mf = 0; mf < MF; ++mf)
#pragma unroll
            for (int nf = 0; nf < 4; ++nf) {
                acc[mf][nf] = __builtin_amdgcn_mfma_f32_16x16x32_bf16(ah[mf], bh[nf],  acc[mf][nf], 0, 0, 0);
                acc[mf][nf] = __builtin_amdgcn_mfma_f32_16x16x32_bf16(ah[mf], blo[nf], acc[mf][nf], 0, 0, 0);
                if constexpr (ASPLIT)
                    acc[mf][nf] = __builtin_amdgcn_mfma_f32_16x16x32_bf16(alo[mf], bh[nf], acc[mf][nf], 0, 0, 0);
            }
        __syncthreads();
    }

    // ---- epilogue: zb (bf16) + el/er ----
    const int h = (bn + wc * 64) >> 6;
    float alv[4], arv[4];
#pragma unroll
    for (int nf = 0; nf < 4; ++nf) {
        alv[nf] = al[h * 64 + nf * 16 + lr];
        arv[nf] = ar[h * 64 + nf * 16 + lr];
    }
#pragma unroll
    for (int mf = 0; mf < MF; ++mf) {
#pragma unroll
        for (int j = 0; j < 4; ++j) {
            int row = bm + wr * MF * 16 + mf * 16 + lg * 4 + j;
            float sel = 0.f, ser = 0.f;
#pragma unroll
            for (int nf = 0; nf < 4; ++nf) {
                float v = acc[mf][nf][j];
                sel += v * alv[nf];
                ser += v * arv[nf];
                if (row < M)
                    zb[(size_t)row * NT + bn + wc * 64 + nf * 16 + lr] = f2bf(v);
            }
#pragma unroll
            for (int off = 1; off <= 8; off <<= 1) {
                sel += __shfl_xor(sel, off);
                ser += __shfl_xor(ser, off);
            }
            if (lr == 0 && row < M) {
                el[(size_t)row * H + h] = sel;
                er[(size_t)row * H + h] = ser;
            }
        }
    }
}

// ---------------- layer-1 aggregate: one wave per node, 4 heads merged --------------
// Gather: 2 edges per dwordx4 load. Lane layout: half = lane>>5 handles even/odd
// edges; lane owns 16B = 8 channels (channels lp*8..lp*8+8, head lp>>3). Final
// shfl_xor(32) butterfly merges even/odd partial sums.

__global__ __launch_bounds__(256) void gat_aggregate_h4(
    const unsigned short* __restrict__ zb,   // [N,256] bf16
    const float* __restrict__ el,            // [N,4]
    const float* __restrict__ er,            // [N,4]
    const int* __restrict__ rowptr, const int* __restrict__ csr_src,
    const float* __restrict__ bias,          // [256]
    unsigned short* __restrict__ out,        // [N,256] bf16 (ELU applied)
    int Nn)
{
    __shared__ float p_lds[4][64][4];
    __shared__ int   s_lds[4][64];
    int wid = threadIdx.x >> 6;
    int lane = threadIdx.x & 63;
    int n = blockIdx.x * 4 + wid;
    if (n >= Nn) return;
    int start = rowptr[n], end = rowptr[n + 1];
    int deg = end - start;
    float4 er4 = *(const float4*)(er + (size_t)n * 4);
    const int half = lane >> 5;                 // 0: even edges, 1: odd edges
    const int lp = lane & 31;                   // position within half
    const int hsel2 = lp >> 3;                  // head of owned channels
    const unsigned lb = (unsigned)(lp << 4);    // byte offset in 512B row

    f32x2 a0 = {0.f, 0.f}, a1 = {0.f, 0.f}, a2 = {0.f, 0.f}, a3 = {0.f, 0.f};
    float4 ssum = make_float4(0.f, 0.f, 0.f, 0.f);
    float m = -INFINITY;

    for (int c0 = 0; c0 < deg; c0 += 64) {
        int nc = min(64, deg - c0);
        int s_l = 0;
        float4 e4 = make_float4(-INFINITY, -INFINITY, -INFINITY, -INFINITY);
        float emax_l = -INFINITY;
        if (lane < nc) {
            s_l = csr_src[start + c0 + lane];
            float4 el4 = *(const float4*)(el + (size_t)s_l * 4);
            e4.x = el4.x + er4.x; e4.x = e4.x > 0.f ? e4.x : 0.2f * e4.x;
            e4.y = el4.y + er4.y; e4.y = e4.y > 0.f ? e4.y : 0.2f * e4.y;
            e4.z = el4.z + er4.z; e4.z = e4.z > 0.f ? e4.z : 0.2f * e4.z;
            e4.w = el4.w + er4.w; e4.w = e4.w > 0.f ? e4.w : 0.2f * e4.w;
            emax_l = fmaxf(fmaxf(e4.x, e4.y), fmaxf(e4.z, e4.w));
        }
        float cm = emax_l;
#pragma unroll
        for (int off = 32; off; off >>= 1) cm = fmaxf(cm, __shfl_xor(cm, off));
        float newm = fmaxf(m, cm);
        float scale = __expf(m - newm);
        ssum.x *= scale; ssum.y *= scale; ssum.z *= scale; ssum.w *= scale;
        f32x2 sc2 = {scale, scale};
        a0 *= sc2; a1 *= sc2; a2 *= sc2; a3 *= sc2;
        m = newm;
        float4 p4 = make_float4(0.f, 0.f, 0.f, 0.f);
        if (lane < nc) {
            p4.x = __expf(e4.x - m);
            p4.y = __expf(e4.y - m);
            p4.z = __expf(e4.z - m);
            p4.w = __expf(e4.w - m);
        }
        float4 cs = p4;
#pragma unroll
        for (int off = 32; off; off >>= 1) {
            cs.x += __shfl_xor(cs.x, off);
            cs.y += __shfl_xor(cs.y, off);
            cs.z += __shfl_xor(cs.z, off);
            cs.w += __shfl_xor(cs.w, off);
        }
        ssum.x += cs.x; ssum.y += cs.y; ssum.z += cs.z; ssum.w += cs.w;
        *(float4*)&p_lds[wid][lane][0] = p4;
        s_lds[wid][lane] = s_l;

        // gather: 4 pairs (8 edges) per batch; half h takes edge 2*(tt+j)+h
        int npairs = (nc + 1) >> 1;
        for (int tt = 0; tt < npairs; tt += 4) {
            float w[4]; unsigned off32[4];
#pragma unroll
            for (int j = 0; j < 4; ++j) {
                int idx = (tt + j) * 2 + half;
                int ic = idx < nc ? idx : 0;
                w[j] = idx < nc ? p_lds[wid][ic][hsel2] : 0.f;
                off32[j] = ((unsigned)s_lds[wid][ic] << 9) + lb;
            }
            uint4 u[4];
#pragma unroll
            for (int j = 0; j < 4; ++j)
                u[j] = *(const uint4*)((const char*)zb + off32[j]);
#pragma unroll
            for (int j = 0; j < 4; ++j) {
                f32x2 ww = {w[j], w[j]};
                f32x2 v;
                v.x = __uint_as_float(u[j].x << 16);
                v.y = __uint_as_float(u[j].x & 0xffff0000u);
                a0 = __builtin_elementwise_fma(ww, v, a0);
                v.x = __uint_as_float(u[j].y << 16);
                v.y = __uint_as_float(u[j].y & 0xffff0000u);
                a1 = __builtin_elementwise_fma(ww, v, a1);
                v.x = __uint_as_float(u[j].z << 16);
                v.y = __uint_as_float(u[j].z & 0xffff0000u);
                a2 = __builtin_elementwise_fma(ww, v, a2);
                v.x = __uint_as_float(u[j].w << 16);
                v.y = __uint_as_float(u[j].w & 0xffff0000u);
                a3 = __builtin_elementwise_fma(ww, v, a3);
            }
        }
    }
    // merge even/odd halves (same channels live in lane lp and lane lp+32)
    a0.x += __shfl_xor(a0.x, 32); a0.y += __shfl_xor(a0.y, 32);
    a1.x += __shfl_xor(a1.x, 32); a1.y += __shfl_xor(a1.y, 32);
    a2.x += __shfl_xor(a2.x, 32); a2.y += __shfl_xor(a2.y, 32);
    a3.x += __shfl_xor(a3.x, 32); a3.y += __shfl_xor(a3.y, 32);

    float s_h = hsel2 == 0 ? ssum.x : hsel2 == 1 ? ssum.y : hsel2 == 2 ? ssum.z : ssum.w;
    float inv = s_h > 0.f ? 1.f / s_h : 0.f;
    if (half == 0) {
        float4 b01 = *(const float4*)(bias + lp * 8);
        float4 b23 = *(const float4*)(bias + lp * 8 + 4);
        float o[8];
        o[0] = a0.x * inv + b01.x; o[1] = a0.y * inv + b01.y;
        o[2] = a1.x * inv + b01.z; o[3] = a1.y * inv + b01.w;
        o[4] = a2.x * inv + b23.x; o[5] = a2.y * inv + b23.y;
        o[6] = a3.x * inv + b23.z; o[7] = a3.y * inv + b23.w;
        short8 ob;
#pragma unroll
        for (int j = 0; j < 8; ++j) {
            float v = o[j] > 0.f ? o[j] : expm1f(o[j]);
            ob[j] = (short)f2bf(v);
        }
        *(short8*)(out + (size_t)n * 256 + lp * 8) = ob;
    }
}

// ---------------- layer-2 aggregate (H=1): 8 edges per dwordx4 load ----------------
// 8 groups of 8 lanes; each lane owns 16B = 8 channels of its group's edge row.

__global__ void gat_aggregate_bf(const unsigned short* __restrict__ zb,  // [N,64] bf16
                                 const float* __restrict__ el, const float* __restrict__ er,
                                 const int* __restrict__ rowptr, const int* __restrict__ csr_src,
                                 const float* __restrict__ bias,
                                 float* __restrict__ out, int Nn)
{
    int gw = (blockIdx.x * blockDim.x + threadIdx.x) >> 6;
    int lane = threadIdx.x & 63;
    int n = gw;
    if (n >= Nn) return;
    int start = rowptr[n], end = rowptr[n + 1];
    int deg = end - start;
    float ern = er[n];

    int group = lane >> 3;                    // 0..7
    int gl = lane & 7;                        // 0..7
    const unsigned lb = (unsigned)(gl << 4);  // 16B per lane in a 128B row

    f32x2 a0 = {0.f, 0.f}, a1 = {0.f, 0.f}, a2 = {0.f, 0.f}, a3 = {0.f, 0.f};
    float m = -INFINITY;
    float ssum = 0.f;

    for (int c0 = 0; c0 < deg; c0 += 64) {
        int nc = min(64, deg - c0);
        int s_l = 0;
        float e_l = -INFINITY;
        if (lane < nc) {
            s_l = csr_src[start + c0 + lane];
            float e = el[s_l] + ern;
            e_l = e > 0.f ? e : 0.2f * e;
        }
        float cm = e_l;
#pragma unroll
        for (int off = 32; off; off >>= 1) cm = fmaxf(cm, __shfl_xor(cm, off));
        float newm = fmaxf(m, cm);
        float scale = __expf(m - newm);
        ssum *= scale;
        f32x2 sc2 = {scale, scale};
        a0 *= sc2; a1 *= sc2; a2 *= sc2; a3 *= sc2;
        m = newm;
        float p_l = (lane < nc) ? __expf(e_l - m) : 0.f;
        float cs = p_l;
#pragma unroll
        for (int off = 32; off; off >>= 1) cs += __shfl_xor(cs, off);
        ssum += cs;

        // 8 groups x 8 edges per pass; batch 2 passes (16 edges) for MLP
        int nIter = (nc + 7) >> 3;
        for (int i0 = 0; i0 < nIter; i0 += 2) {
            float w[2]; unsigned off32[2];
#pragma unroll
            for (int j = 0; j < 2; ++j) {
                int tt = group + 8 * (i0 + j);
                int tc = tt & 63;
                float wv = __shfl(p_l, tc);
                int s = __shfl(s_l, tc);
                w[j] = (tt < nc) ? wv : 0.f;
                off32[j] = ((unsigned)s << 7) + lb;
            }
            uint4 u[2];
#pragma unroll
            for (int j = 0; j < 2; ++j)
                u[j] = *(const uint4*)((const char*)zb + off32[j]);
#pragma unroll
            for (int j = 0; j < 2; ++j) {
                f32x2 ww = {w[j], w[j]};
                f32x2 v;
                v.x = __uint_as_float(u[j].x << 16);
                v.y = __uint_as_float(u[j].x & 0xffff0000u);
                a0 = __builtin_elementwise_fma(ww, v, a0);
                v.x = __uint_as_float(u[j].y << 16);
                v.y = __uint_as_float(u[j].y & 0xffff0000u);
                a1 = __builtin_elementwise_fma(ww, v, a1);
                v.x = __uint_as_float(u[j].z << 16);
                v.y = __uint_as_float(u[j].z & 0xffff0000u);
                a2 = __builtin_elementwise_fma(ww, v, a2);
                v.x = __uint_as_float(u[j].w << 16);
                v.y = __uint_as_float(u[j].w & 0xffff0000u);
                a3 = __builtin_elementwise_fma(ww, v, a3);
            }
        }
    }
    // merge the 8 groups: butterfly over lane bits 3,4,5
#pragma unroll
    for (int off = 8; off <= 32; off <<= 1) {
        a0.x += __shfl_xor(a0.x, off); a0.y += __shfl_xor(a0.y, off);
        a1.x += __shfl_xor(a1.x, off); a1.y += __shfl_xor(a1.y, off);
        a2.x += __shfl_xor(a2.x, off); a2.y += __shfl_xor(a2.y, off);
        a3.x += __shfl_xor(a3.x, off); a3.y += __shfl_xor(a3.y, off);
    }
    float inv = ssum > 0.f ? 1.f / ssum : 0.f;
    if (lane < 8) {
        float4 o0, o1;
        o0.x = a0.x * inv + bias[gl * 8 + 0];
        o0.y = a0.y * inv + bias[gl * 8 + 1];
        o0.z = a1.x * inv + bias[gl * 8 + 2];
        o0.w = a1.y * inv + bias[gl * 8 + 3];
        o1.x = a2.x * inv + bias[gl * 8 + 4];
        o1.y = a2.y * inv + bias[gl * 8 + 5];
        o1.z = a3.x * inv + bias[gl * 8 + 6];
        o1.w = a3.y * inv + bias[gl * 8 + 7];
        *(float4*)(out + (size_t)n * 64 + gl * 8) = o0;
        *(float4*)(out + (size_t)n * 64 + gl * 8 + 4) = o1;
    }
}

// ---------------- launch ----------------

static inline size_t align_up(size_t x, size_t a) { return (x + a - 1) & ~(a - 1); }

extern "C" void kernel_launch(void* const* d_in, const int* in_sizes, int n_in,
                              void* d_out, int out_size, void* d_ws, size_t ws_size,
                              hipStream_t stream) {
    const float* x   = (const float*)d_in[0];
    const float* W1  = (const float*)d_in[1];
    const float* al1 = (const float*)d_in[2];
    const float* ar1 = (const float*)d_in[3];
    const float* b1  = (const float*)d_in[4];
    const float* W2  = (const float*)d_in[5];
    const float* al2 = (const float*)d_in[6];
    const float* ar2 = (const float*)d_in[7];
    const float* b2  = (const float*)d_in[8];
    const int*   src = (const int*)d_in[9];
    const int*   dst = (const int*)d_in[10];
    float* out = (float*)d_out;

    char* ws = (char*)d_ws;
    size_t off = 0;
    unsigned short* zb1 = (unsigned short*)(ws + off); off = align_up(off + (size_t)NN * 256 * 2, 256);
    unsigned short* h1b = (unsigned short*)(ws + off); off = align_up(off + (size_t)NN * 256 * 2, 256);
    unsigned short* zb2 = (unsigned short*)(ws + off); off = align_up(off + (size_t)NN * 64 * 2, 256);
    float* el1 = (float*)(ws + off); off = align_up(off + (size_t)NN * H1 * 4, 256);
    float* er1 = (float*)(ws + off); off = align_up(off + (size_t)NN * H1 * 4, 256);
    float* el2 = (float*)(ws + off); off = align_up(off + (size_t)NN * 4, 256);
    float* er2 = (float*)(ws + off); off = align_up(off + (size_t)NN * 4, 256);
    short* W1th = (short*)(ws + off); off = align_up(off + 256 * 256 * 2, 256);
    short* W1tl = (short*)(ws + off); off = align_up(off + 256 * 256 * 2, 256);
    short* W2th = (short*)(ws + off); off = align_up(off + 64 * 256 * 2, 256);
    short* W2tl = (short*)(ws + off); off = align_up(off + 64 * 256 * 2, 256);
    int* rowptr = (int*)(ws + off); off = align_up(off + (size_t)(NN + 1) * 4, 256);
    int* deg    = (int*)(ws + off); off = align_up(off + (size_t)NN * 4, 256);
    int* fillc  = (int*)(ws + off); off = align_up(off + (size_t)NN * 4, 256);
    int* bsums  = (int*)(ws + off); off = align_up(off + 256 * 4, 256);
    int* csr_src = (int*)(ws + off); off = align_up(off + (size_t)EE * 4, 256);

    const int nScanBlocks = (NN + 255) / 256;
    const int nEdgeBlocks = (EE + 255) / 256;
    const int nMBlocks64 = (NN + 63) / 64;     // 782
    const int nMBlocks128 = (NN + 127) / 128;  // 391

    hipMemsetAsync(deg, 0, (size_t)NN * 4, stream);
    hipMemsetAsync(fillc, 0, (size_t)NN * 4, stream);
    wsplit<<<320, 256, 0, stream>>>(W1, W2, W1th, W1tl, W2th, W2tl);
    hist_kernel<<<nEdgeBlocks, 256, 0, stream>>>(dst, deg, EE);
    scan_block<<<nScanBlocks, 256, 0, stream>>>(deg, rowptr, bsums, NN);
    scan_bsums<<<1, 256, 0, stream>>>(bsums, nScanBlocks);
    add_offsets<<<nScanBlocks, 256, 0, stream>>>(rowptr, bsums, NN, EE);
    fill_csr<<<nEdgeBlocks, 256, 0, stream>>>(src, dst, rowptr, fillc, csr_src, EE);

    // ---- layer 1: BN=256 (single A pass) ----
    gemm_bf16x2<4, 1, 4, 256, 4, true><<<dim3(nMBlocks64, 1), 256, 0, stream>>>(
        x, W1th, W1tl, al1, ar1, zb1, el1, er1, NN, FIN);
    gat_aggregate_h4<<<(NN + 3) / 4, 256, 0, stream>>>(
        zb1, el1, er1, rowptr, csr_src, b1, h1b, NN);

    // ---- layer 2 ----
    gemm_bf16x2<2, 4, 1, 64, 1, false><<<dim3(nMBlocks128, 1), 256, 0, stream>>>(
        h1b, W2th, W2tl, al2, ar2, zb2, el2, er2, NN, H1 * HID);
    gat_aggregate_bf<<<(NN * 64 + 255) / 256, 256, 0, stream>>>(
        zb2, el2, er2, rowptr, csr_src, b2, out, NN);
}